// Round 2
// baseline (734.813 us; speedup 1.0000x reference)
//
#include <hip/hip_runtime.h>
#include <hip/hip_bf16.h>
#include <cstddef>

// Problem constants (fixed by setup_inputs)
#define BATCH 4
#define CCH 256
#define NHEAD 8
#define DHEAD 32
#define NZ 1024
#define NX 4096
#define NTOK 5120          // NZ + NX
#define LKV 1280           // 256 (z after SR) + 1024 (x after SR)
#define SCALE 0.17677669529663687f

// ---------------- Wsr reorder: Wk[co][di*512+dj*256+ci] = Wsr[co][ci][di][dj]
__global__ __launch_bounds__(256) void reorder_wsr(const float* __restrict__ Wsr,
                                                   float* __restrict__ Wk) {
  int i = blockIdx.x * 256 + threadIdx.x;    // 256*1024 total
  int co = i >> 10;
  int rem = i & 1023;
  int di = rem >> 9, dj = (rem >> 8) & 1, ci = rem & 255;
  Wk[i] = Wsr[((co * 256 + ci) * 2 + di) * 2 + dj];
}

// ---------------- im2col for the stride-2 2x2 conv, rows in cat order (z first)
__global__ __launch_bounds__(256) void im2col_kernel(const float* __restrict__ x,
                                                     float* __restrict__ patch) {
  int blk = blockIdx.x;            // b*1280 + t
  int b = blk / 1280, t = blk % 1280;
  int c = threadIdx.x;
#pragma unroll
  for (int di = 0; di < 2; ++di)
#pragma unroll
    for (int dj = 0; dj < 2; ++dj) {
      int src;
      if (t < 256) {                      // z branch: 32x32 -> 16x16
        int oi = t >> 4, oj = t & 15;
        src = b * NTOK + (2 * oi + di) * 32 + (2 * oj + dj);
      } else {                            // x branch: 64x64 -> 32x32
        int tt = t - 256;
        int oi = tt >> 5, oj = tt & 31;
        src = b * NTOK + NZ + (2 * oi + di) * 64 + (2 * oj + dj);
      }
      patch[(size_t)blk * 1024 + di * 512 + dj * 256 + c] = x[(size_t)src * CCH + c];
    }
}

// ---------------- fp32 GEMM:  C[m,n] = sum_k A[m,k]*B[n,k] (+bias[n])
// A: (M,K) row-major, B: (N,K) row-major. M%64==0, N%64==0, K%16==0.
#define BM 64
#define BN 64
#define BK 16
__global__ __launch_bounds__(256) void gemm_nt(const float* __restrict__ A,
                                               const float* __restrict__ Bm,
                                               const float* __restrict__ bias,
                                               float* __restrict__ Cm,
                                               int M, int N, int K) {
  __shared__ float As[BK][BM + 4];   // row stride 68 floats = 272B (16B aligned)
  __shared__ float Bs[BK][BN + 4];
  int bm = blockIdx.y * BM, bn = blockIdx.x * BN;
  int tid = threadIdx.x;
  int tm = (tid >> 4) << 2;
  int tn = (tid & 15) << 2;
  int lr = tid >> 2;          // 0..63 : tile row for loading
  int lq = tid & 3;           // k-quad
  const float* Aptr = A + (size_t)(bm + lr) * K + lq * 4;
  const float* Bptr = Bm + (size_t)(bn + lr) * K + lq * 4;
  float acc[4][4];
#pragma unroll
  for (int i = 0; i < 4; ++i)
#pragma unroll
    for (int j = 0; j < 4; ++j) acc[i][j] = 0.f;

  for (int k0 = 0; k0 < K; k0 += BK) {
    float4 av = *(const float4*)(Aptr + k0);
    float4 bv = *(const float4*)(Bptr + k0);
    __syncthreads();
    As[lq * 4 + 0][lr] = av.x; As[lq * 4 + 1][lr] = av.y;
    As[lq * 4 + 2][lr] = av.z; As[lq * 4 + 3][lr] = av.w;
    Bs[lq * 4 + 0][lr] = bv.x; Bs[lq * 4 + 1][lr] = bv.y;
    Bs[lq * 4 + 2][lr] = bv.z; Bs[lq * 4 + 3][lr] = bv.w;
    __syncthreads();
#pragma unroll
    for (int kk = 0; kk < BK; ++kk) {
      float4 a4 = *(const float4*)&As[kk][tm];
      float4 b4 = *(const float4*)&Bs[kk][tn];
      float aa[4] = {a4.x, a4.y, a4.z, a4.w};
      float bb[4] = {b4.x, b4.y, b4.z, b4.w};
#pragma unroll
      for (int i = 0; i < 4; ++i)
#pragma unroll
        for (int j = 0; j < 4; ++j) acc[i][j] += aa[i] * bb[j];
    }
  }
#pragma unroll
  for (int i = 0; i < 4; ++i) {
    float4 o;
    float b0 = bias ? bias[bn + tn + 0] : 0.f;
    float b1 = bias ? bias[bn + tn + 1] : 0.f;
    float b2 = bias ? bias[bn + tn + 2] : 0.f;
    float b3 = bias ? bias[bn + tn + 3] : 0.f;
    o.x = acc[i][0] + b0; o.y = acc[i][1] + b1;
    o.z = acc[i][2] + b2; o.w = acc[i][3] + b3;
    *(float4*)(Cm + (size_t)(bm + tm + i) * N + bn + tn) = o;
  }
}

// ---------------- bias + LayerNorm over C=256, in place on cat
__global__ __launch_bounds__(256) void bias_ln_kernel(float* __restrict__ cat,
                                                      const float* __restrict__ bsr,
                                                      const float* __restrict__ gamma,
                                                      const float* __restrict__ beta) {
  int row = blockIdx.x;
  int c = threadIdx.x;
  __shared__ float red[256];
  float v = cat[(size_t)row * 256 + c] + bsr[c];
  red[c] = v;
  __syncthreads();
#pragma unroll
  for (int s = 128; s > 0; s >>= 1) {
    if (c < s) red[c] += red[c + s];
    __syncthreads();
  }
  float mu = red[0] * (1.f / 256.f);
  __syncthreads();
  float dv = v - mu;
  red[c] = dv * dv;
  __syncthreads();
#pragma unroll
  for (int s = 128; s > 0; s >>= 1) {
    if (c < s) red[c] += red[c + s];
    __syncthreads();
  }
  float var = red[0] * (1.f / 256.f);
  float rs = rsqrtf(var + 1e-5f);
  cat[(size_t)row * 256 + c] = dv * rs * gamma[c] + beta[c];
}

// ---------------- flash attention, fp32. One block = 64 q rows of one (b,h).
#define TQ 64
#define TK 64
__global__ __launch_bounds__(256) void attn_kernel(const float* __restrict__ q,
                                                   const float* __restrict__ kv,
                                                   float* __restrict__ out,
                                                   int q0, int kvlen) {
  int tiles = gridDim.x / 32;              // q tiles per (b,h)
  int bh = blockIdx.x / tiles;
  int qt = blockIdx.x % tiles;
  int b = bh >> 3, hh = bh & 7;
  int tid = threadIdx.x;

  __shared__ float Qst[32][68];            // k-major, 16B-aligned rows
  __shared__ float Kst[32][68];
  __shared__ float Vs[TK][36];             // row stride 144B (16B aligned)
  __shared__ float Ps[TQ][65];
  __shared__ float m_s[TQ], l_s[TQ], alpha_s[TQ];
  __shared__ float pmax[TQ][4], psum[TQ][4];

  int qrow0 = b * NTOK + q0 + qt * TQ;
  for (int i = tid; i < 512; i += 256) {
    int r = i >> 3, c4 = i & 7;
    float4 v = *(const float4*)(q + (size_t)(qrow0 + r) * CCH + hh * DHEAD + c4 * 4);
    Qst[c4 * 4 + 0][r] = v.x; Qst[c4 * 4 + 1][r] = v.y;
    Qst[c4 * 4 + 2][r] = v.z; Qst[c4 * 4 + 3][r] = v.w;
  }
  if (tid < TQ) { m_s[tid] = -1e30f; l_s[tid] = 0.f; }

  int tm = (tid >> 4) << 2, tn = (tid & 15) << 2;
  int r2 = (tid >> 3) << 1;                // stage-2 row pair
  int ddb = tid & 7;                        // stage-2 dd block (4 floats)
  float o[2][4] = {{0, 0, 0, 0}, {0, 0, 0, 0}};

  for (int l0 = 0; l0 < kvlen; l0 += TK) {
    __syncthreads();                        // prev stage2 done; Qst visible
    for (int i = tid; i < 512; i += 256) {
      int r = i >> 3, c4 = i & 7;
      const float* base = kv + (size_t)(b * LKV + l0 + r) * 512;
      float4 kk4 = *(const float4*)(base + hh * DHEAD + c4 * 4);
      Kst[c4 * 4 + 0][r] = kk4.x; Kst[c4 * 4 + 1][r] = kk4.y;
      Kst[c4 * 4 + 2][r] = kk4.z; Kst[c4 * 4 + 3][r] = kk4.w;
      float4 vv = *(const float4*)(base + 256 + hh * DHEAD + c4 * 4);
      *(float4*)&Vs[r][c4 * 4] = vv;
    }
    __syncthreads();
    // stage 1: S = scale * Q K^T  (64x64, K=32)
    float acc[4][4];
#pragma unroll
    for (int i = 0; i < 4; ++i)
#pragma unroll
      for (int j = 0; j < 4; ++j) acc[i][j] = 0.f;
#pragma unroll
    for (int kk = 0; kk < 32; ++kk) {
      float4 a4 = *(const float4*)&Qst[kk][tm];
      float4 b4 = *(const float4*)&Kst[kk][tn];
      float aa[4] = {a4.x, a4.y, a4.z, a4.w};
      float bb[4] = {b4.x, b4.y, b4.z, b4.w};
#pragma unroll
      for (int i = 0; i < 4; ++i)
#pragma unroll
        for (int j = 0; j < 4; ++j) acc[i][j] += aa[i] * bb[j];
    }
#pragma unroll
    for (int i = 0; i < 4; ++i)
#pragma unroll
      for (int j = 0; j < 4; ++j) Ps[tm + i][tn + j] = acc[i][j] * SCALE;
    __syncthreads();
    // row max partials
    {
      int r = tid >> 2, seg = tid & 3;
      float mx = -1e30f;
#pragma unroll
      for (int c = 0; c < 16; ++c) mx = fmaxf(mx, Ps[r][seg * 16 + c]);
      pmax[r][seg] = mx;
    }
    __syncthreads();
    if (tid < TQ) {
      float mx = fmaxf(fmaxf(pmax[tid][0], pmax[tid][1]),
                       fmaxf(pmax[tid][2], pmax[tid][3]));
      float mold = m_s[tid];
      float mnew = fmaxf(mold, mx);
      float alpha = __expf(mold - mnew);
      m_s[tid] = mnew;
      alpha_s[tid] = alpha;
      l_s[tid] *= alpha;
    }
    __syncthreads();
    {
      int r = tid >> 2, seg = tid & 3;
      float mrow = m_s[r];
      float s = 0.f;
#pragma unroll
      for (int c = 0; c < 16; ++c) {
        float p = __expf(Ps[r][seg * 16 + c] - mrow);
        Ps[r][seg * 16 + c] = p;
        s += p;
      }
      psum[r][seg] = s;
    }
    __syncthreads();
    if (tid < TQ)
      l_s[tid] += psum[tid][0] + psum[tid][1] + psum[tid][2] + psum[tid][3];
    // stage 2: O = O*alpha + P V  (64x32, K=64)
    float a0 = alpha_s[r2], a1 = alpha_s[r2 + 1];
#pragma unroll
    for (int j = 0; j < 4; ++j) { o[0][j] *= a0; o[1][j] *= a1; }
    for (int l = 0; l < TK; ++l) {
      float p0 = Ps[r2][l], p1 = Ps[r2 + 1][l];
      float4 v4 = *(const float4*)&Vs[l][ddb * 4];
      o[0][0] += p0 * v4.x; o[0][1] += p0 * v4.y;
      o[0][2] += p0 * v4.z; o[0][3] += p0 * v4.w;
      o[1][0] += p1 * v4.x; o[1][1] += p1 * v4.y;
      o[1][2] += p1 * v4.z; o[1][3] += p1 * v4.w;
    }
  }
  __syncthreads();
  float inv0 = 1.f / l_s[r2];
  float inv1 = 1.f / l_s[r2 + 1];
  float4 o0, o1;
  o0.x = o[0][0] * inv0; o0.y = o[0][1] * inv0;
  o0.z = o[0][2] * inv0; o0.w = o[0][3] * inv0;
  o1.x = o[1][0] * inv1; o1.y = o[1][1] * inv1;
  o1.z = o[1][2] * inv1; o1.w = o[1][3] * inv1;
  *(float4*)(out + (size_t)(qrow0 + r2) * CCH + hh * DHEAD + ddb * 4) = o0;
  *(float4*)(out + (size_t)(qrow0 + r2 + 1) * CCH + hh * DHEAD + ddb * 4) = o1;
}

extern "C" void kernel_launch(void* const* d_in, const int* in_sizes, int n_in,
                              void* d_out, int out_size, void* d_ws, size_t ws_size,
                              hipStream_t stream) {
  (void)in_sizes; (void)n_in; (void)out_size; (void)ws_size;
  const float* x     = (const float*)d_in[0];
  const float* Wq    = (const float*)d_in[1];
  const float* Wkv   = (const float*)d_in[2];
  const float* Wsr   = (const float*)d_in[3];
  const float* bsr   = (const float*)d_in[4];
  const float* gamma = (const float*)d_in[5];
  const float* beta  = (const float*)d_in[6];
  const float* Wproj = (const float*)d_in[7];
  const float* bproj = (const float*)d_in[8];
  float* out = (float*)d_out;
  float* ws  = (float*)d_ws;

  float* q_buf    = ws;                          // 5,242,880 f
  float* patch    = ws + 5242880;                // 5,242,880 f (reused as attn_out)
  float* attn_out = patch;
  float* Wk       = ws + 10485760;               //   262,144 f
  float* cat      = ws + 10747904;               // 1,310,720 f
  float* kvb      = ws + 12058624;               // 2,621,440 f  (end: 14,680,064 f = 58.7MB)

  reorder_wsr<<<1024, 256, 0, stream>>>(Wsr, Wk);
  im2col_kernel<<<BATCH * LKV, 256, 0, stream>>>(x, patch);
  // q = x @ Wq^T                       (20480 x 256, K=256)
  gemm_nt<<<dim3(4, 320), 256, 0, stream>>>(x, Wq, nullptr, q_buf, BATCH * NTOK, 256, 256);
  // conv as GEMM                       (5120 x 256, K=1024)
  gemm_nt<<<dim3(4, 80), 256, 0, stream>>>(patch, Wk, nullptr, cat, BATCH * LKV, 256, 1024);
  bias_ln_kernel<<<BATCH * LKV, 256, 0, stream>>>(cat, bsr, gamma, beta);
  // kv = cat @ Wkv^T                   (5120 x 512, K=256)
  gemm_nt<<<dim3(8, 80), 256, 0, stream>>>(cat, Wkv, nullptr, kvb, BATCH * LKV, 512, 256);
  // attention: z-part (1024 q rows vs 256 kv), x-part (4096 q rows vs 1280 kv)
  attn_kernel<<<512, 256, 0, stream>>>(q_buf, kvb, attn_out, 0, 256);
  attn_kernel<<<2048, 256, 0, stream>>>(q_buf, kvb, attn_out, NZ, LKV);
  // out = attn_out @ Wproj^T + bproj   (20480 x 256, K=256)
  gemm_nt<<<dim3(4, 320), 256, 0, stream>>>(attn_out, Wproj, bproj, out, BATCH * NTOK, 256, 256);
}

// Round 3
// 405.796 us; speedup vs baseline: 1.8108x; 1.8108x over previous
//
#include <hip/hip_runtime.h>
#include <hip/hip_bf16.h>
#include <cstddef>

// Problem constants (fixed by setup_inputs)
#define BATCH 4
#define CCH 256
#define NHEAD 8
#define DHEAD 32
#define NZ 1024
#define NX 4096
#define NTOK 5120          // NZ + NX
#define LKV 1280           // 256 (z after SR) + 1024 (x after SR)
#define SCALE 0.17677669529663687f

typedef __attribute__((ext_vector_type(8))) short bf16x8;
typedef __attribute__((ext_vector_type(4))) float floatx4;

__device__ inline short f2bf(float f) {
  __hip_bfloat16 h = __float2bfloat16(f);
  return __builtin_bit_cast(short, h);
}

// ---------------- Wsr reorder: Wk[co][di*512+dj*256+ci] = Wsr[co][ci][di][dj]
__global__ __launch_bounds__(256) void reorder_wsr(const float* __restrict__ Wsr,
                                                   float* __restrict__ Wk) {
  int i = blockIdx.x * 256 + threadIdx.x;    // 256*1024 total
  int co = i >> 10;
  int rem = i & 1023;
  int di = rem >> 9, dj = (rem >> 8) & 1, ci = rem & 255;
  Wk[i] = Wsr[((co * 256 + ci) * 2 + di) * 2 + dj];
}

// ---------------- im2col for the stride-2 2x2 conv, rows in cat order (z first)
__global__ __launch_bounds__(256) void im2col_kernel(const float* __restrict__ x,
                                                     float* __restrict__ patch) {
  int blk = blockIdx.x;            // b*1280 + t
  int b = blk / 1280, t = blk % 1280;
  int c = threadIdx.x;
#pragma unroll
  for (int di = 0; di < 2; ++di)
#pragma unroll
    for (int dj = 0; dj < 2; ++dj) {
      int src;
      if (t < 256) {                      // z branch: 32x32 -> 16x16
        int oi = t >> 4, oj = t & 15;
        src = b * NTOK + (2 * oi + di) * 32 + (2 * oj + dj);
      } else {                            // x branch: 64x64 -> 32x32
        int tt = t - 256;
        int oi = tt >> 5, oj = tt & 31;
        src = b * NTOK + NZ + (2 * oi + di) * 64 + (2 * oj + dj);
      }
      patch[(size_t)blk * 1024 + di * 512 + dj * 256 + c] = x[(size_t)src * CCH + c];
    }
}

// ---------------- fp32 GEMM:  C[m,n] = sum_k A[m,k]*B[n,k] (+bias[n])
#define BM 64
#define BN 64
#define BK 16
__global__ __launch_bounds__(256) void gemm_nt(const float* __restrict__ A,
                                               const float* __restrict__ Bm,
                                               const float* __restrict__ bias,
                                               float* __restrict__ Cm,
                                               int M, int N, int K) {
  __shared__ float As[BK][BM + 4];
  __shared__ float Bs[BK][BN + 4];
  int bm = blockIdx.y * BM, bn = blockIdx.x * BN;
  int tid = threadIdx.x;
  int tm = (tid >> 4) << 2;
  int tn = (tid & 15) << 2;
  int lr = tid >> 2;
  int lq = tid & 3;
  const float* Aptr = A + (size_t)(bm + lr) * K + lq * 4;
  const float* Bptr = Bm + (size_t)(bn + lr) * K + lq * 4;
  float acc[4][4];
#pragma unroll
  for (int i = 0; i < 4; ++i)
#pragma unroll
    for (int j = 0; j < 4; ++j) acc[i][j] = 0.f;

  for (int k0 = 0; k0 < K; k0 += BK) {
    float4 av = *(const float4*)(Aptr + k0);
    float4 bv = *(const float4*)(Bptr + k0);
    __syncthreads();
    As[lq * 4 + 0][lr] = av.x; As[lq * 4 + 1][lr] = av.y;
    As[lq * 4 + 2][lr] = av.z; As[lq * 4 + 3][lr] = av.w;
    Bs[lq * 4 + 0][lr] = bv.x; Bs[lq * 4 + 1][lr] = bv.y;
    Bs[lq * 4 + 2][lr] = bv.z; Bs[lq * 4 + 3][lr] = bv.w;
    __syncthreads();
#pragma unroll
    for (int kk = 0; kk < BK; ++kk) {
      float4 a4 = *(const float4*)&As[kk][tm];
      float4 b4 = *(const float4*)&Bs[kk][tn];
      float aa[4] = {a4.x, a4.y, a4.z, a4.w};
      float bb[4] = {b4.x, b4.y, b4.z, b4.w};
#pragma unroll
      for (int i = 0; i < 4; ++i)
#pragma unroll
        for (int j = 0; j < 4; ++j) acc[i][j] += aa[i] * bb[j];
    }
  }
#pragma unroll
  for (int i = 0; i < 4; ++i) {
    float4 o;
    float b0 = bias ? bias[bn + tn + 0] : 0.f;
    float b1 = bias ? bias[bn + tn + 1] : 0.f;
    float b2 = bias ? bias[bn + tn + 2] : 0.f;
    float b3 = bias ? bias[bn + tn + 3] : 0.f;
    o.x = acc[i][0] + b0; o.y = acc[i][1] + b1;
    o.z = acc[i][2] + b2; o.w = acc[i][3] + b3;
    *(float4*)(Cm + (size_t)(bm + tm + i) * N + bn + tn) = o;
  }
}

// ---------------- bias + LayerNorm over C=256, in place on cat
__global__ __launch_bounds__(256) void bias_ln_kernel(float* __restrict__ cat,
                                                      const float* __restrict__ bsr,
                                                      const float* __restrict__ gamma,
                                                      const float* __restrict__ beta) {
  int row = blockIdx.x;
  int c = threadIdx.x;
  __shared__ float red[256];
  float v = cat[(size_t)row * 256 + c] + bsr[c];
  red[c] = v;
  __syncthreads();
#pragma unroll
  for (int s = 128; s > 0; s >>= 1) {
    if (c < s) red[c] += red[c + s];
    __syncthreads();
  }
  float mu = red[0] * (1.f / 256.f);
  __syncthreads();
  float dv = v - mu;
  red[c] = dv * dv;
  __syncthreads();
#pragma unroll
  for (int s = 128; s > 0; s >>= 1) {
    if (c < s) red[c] += red[c + s];
    __syncthreads();
  }
  float var = red[0] * (1.f / 256.f);
  float rs = rsqrtf(var + 1e-5f);
  cat[(size_t)row * 256 + c] = dv * rs * gamma[c] + beta[c];
}

// ---------------- MFMA bf16 flash attention.
// One block = 256 thr = 4 waves; each wave owns 16 q rows; KV tile = 64.
// Q/K A,B-frag layout for mfma_f32_16x16x32_bf16: row = lane&15, k-chunk 8*(lane>>4).
// C/D layout: col = lane&15, row = 4*(lane>>4)+reg  [m89/m91 verified mapping].
__global__ __launch_bounds__(256) void attn_mfma(const float* __restrict__ q,
                                                 const float* __restrict__ kvb,
                                                 float* __restrict__ out,
                                                 int q0, int kvlen, int tiles) {
  int bh = blockIdx.x / tiles;
  int qt = blockIdx.x % tiles;
  int b = bh >> 3, hh = bh & 7;
  int tid = threadIdx.x;
  int wave = tid >> 6, lane = tid & 63, lg = lane >> 4, lr = lane & 15;

  __shared__ __align__(16) short Ks[64][40];    // K tile, row stride 80B (2-way bank alias: free)
  __shared__ __align__(16) short Vt[32][72];    // V tile transposed [d][kv], row 144B
  __shared__ __align__(16) short Ps[4][16][72]; // per-wave P round-trip (C-layout -> A-layout)

  int qrow0 = b * NTOK + q0 + qt * 64;
  size_t bkv = (size_t)b * LKV;

  // Q fragment: wave's 16 rows, register resident for whole kernel
  bf16x8 qf;
  {
    const float* qp = q + (size_t)(qrow0 + wave * 16 + lr) * CCH + hh * DHEAD + lg * 8;
    float4 a = *(const float4*)qp;
    float4 c = *(const float4*)(qp + 4);
    qf[0] = f2bf(a.x); qf[1] = f2bf(a.y); qf[2] = f2bf(a.z); qf[3] = f2bf(a.w);
    qf[4] = f2bf(c.x); qf[5] = f2bf(c.y); qf[6] = f2bf(c.z); qf[7] = f2bf(c.w);
  }

  floatx4 oacc[2] = {{0.f, 0.f, 0.f, 0.f}, {0.f, 0.f, 0.f, 0.f}};
  float mrow[4] = {-1e30f, -1e30f, -1e30f, -1e30f};
  float lrow[4] = {0.f, 0.f, 0.f, 0.f};

  for (int l0 = 0; l0 < kvlen; l0 += 64) {
    __syncthreads();                       // prior iteration's K/V reads complete
    // ---- stage K: 64 rows x 32 d, bf16
    {
      int r = tid >> 2, dch = tid & 3;
      const float* kp = kvb + (bkv + l0 + r) * 512 + hh * DHEAD + dch * 8;
      float4 a = *(const float4*)kp;
      float4 c = *(const float4*)(kp + 4);
      bf16x8 k8;
      k8[0] = f2bf(a.x); k8[1] = f2bf(a.y); k8[2] = f2bf(a.z); k8[3] = f2bf(a.w);
      k8[4] = f2bf(c.x); k8[5] = f2bf(c.y); k8[6] = f2bf(c.z); k8[7] = f2bf(c.w);
      *(bf16x8*)&Ks[r][dch * 8] = k8;
    }
    // ---- stage V transposed: Vt[d][kv]
    {
      int d = tid & 31, r0 = (tid >> 5) * 8;
      bf16x8 v8;
#pragma unroll
      for (int j = 0; j < 8; ++j)
        v8[j] = f2bf(kvb[(bkv + l0 + r0 + j) * 512 + 256 + hh * DHEAD + d]);
      *(bf16x8*)&Vt[d][r0] = v8;
    }
    __syncthreads();

    // ---- S = Q K^T  (16q x 64kv per wave, 4 MFMAs)
    floatx4 sc[4];
#pragma unroll
    for (int m = 0; m < 4; ++m) {
      bf16x8 kf = *(bf16x8*)&Ks[m * 16 + lr][lg * 8];
      sc[m] = __builtin_amdgcn_mfma_f32_16x16x32_bf16(qf, kf, (floatx4){0.f, 0.f, 0.f, 0.f}, 0, 0, 0);
    }

    // ---- online softmax (row r_local = 4*lg + reg; 16 lanes per row via lr)
#pragma unroll
    for (int reg = 0; reg < 4; ++reg) {
      float t0 = fmaxf(fmaxf(sc[0][reg], sc[1][reg]), fmaxf(sc[2][reg], sc[3][reg])) * SCALE;
#pragma unroll
      for (int mask = 1; mask < 16; mask <<= 1)
        t0 = fmaxf(t0, __shfl_xor(t0, mask, 64));
      float mo = mrow[reg];
      float mn = fmaxf(mo, t0);
      float alpha = __expf(mo - mn);
      mrow[reg] = mn;
      float rs = 0.f;
      int pr = lg * 4 + reg;
#pragma unroll
      for (int m = 0; m < 4; ++m) {
        float p = __expf(fmaf(sc[m][reg], SCALE, -mn));
        rs += p;
        Ps[wave][pr][lr + 16 * m] = f2bf(p);
      }
#pragma unroll
      for (int mask = 1; mask < 16; mask <<= 1)
        rs += __shfl_xor(rs, mask, 64);
      lrow[reg] = lrow[reg] * alpha + rs;
      oacc[0][reg] *= alpha;
      oacc[1][reg] *= alpha;
    }

    // ---- O += P V  (16q x 32d per wave, 4 MFMAs; K-dim 64 in 2 halves)
#pragma unroll
    for (int kb = 0; kb < 2; ++kb) {
      bf16x8 pf = *(bf16x8*)&Ps[wave][lr][kb * 32 + lg * 8];
#pragma unroll
      for (int n = 0; n < 2; ++n) {
        bf16x8 vf = *(bf16x8*)&Vt[n * 16 + lr][kb * 32 + lg * 8];
        oacc[n] = __builtin_amdgcn_mfma_f32_16x16x32_bf16(pf, vf, oacc[n], 0, 0, 0);
      }
    }
  }

  // ---- epilogue: O / l
#pragma unroll
  for (int reg = 0; reg < 4; ++reg) {
    float inv = 1.f / lrow[reg];
    int gr = qrow0 + wave * 16 + lg * 4 + reg;
    out[(size_t)gr * CCH + hh * DHEAD + lr]      = oacc[0][reg] * inv;
    out[(size_t)gr * CCH + hh * DHEAD + 16 + lr] = oacc[1][reg] * inv;
  }
}

extern "C" void kernel_launch(void* const* d_in, const int* in_sizes, int n_in,
                              void* d_out, int out_size, void* d_ws, size_t ws_size,
                              hipStream_t stream) {
  (void)in_sizes; (void)n_in; (void)out_size; (void)ws_size;
  const float* x     = (const float*)d_in[0];
  const float* Wq    = (const float*)d_in[1];
  const float* Wkv   = (const float*)d_in[2];
  const float* Wsr   = (const float*)d_in[3];
  const float* bsr   = (const float*)d_in[4];
  const float* gamma = (const float*)d_in[5];
  const float* beta  = (const float*)d_in[6];
  const float* Wproj = (const float*)d_in[7];
  const float* bproj = (const float*)d_in[8];
  float* out = (float*)d_out;
  float* ws  = (float*)d_ws;

  float* q_buf    = ws;                          // 5,242,880 f
  float* patch    = ws + 5242880;                // 5,242,880 f (reused as attn_out)
  float* attn_out = patch;
  float* Wk       = ws + 10485760;               //   262,144 f
  float* cat      = ws + 10747904;               // 1,310,720 f
  float* kvb      = ws + 12058624;               // 2,621,440 f

  reorder_wsr<<<1024, 256, 0, stream>>>(Wsr, Wk);
  im2col_kernel<<<BATCH * LKV, 256, 0, stream>>>(x, patch);
  // q = x @ Wq^T                       (20480 x 256, K=256)
  gemm_nt<<<dim3(4, 320), 256, 0, stream>>>(x, Wq, nullptr, q_buf, BATCH * NTOK, 256, 256);
  // conv as GEMM                       (5120 x 256, K=1024)
  gemm_nt<<<dim3(4, 80), 256, 0, stream>>>(patch, Wk, nullptr, cat, BATCH * LKV, 256, 1024);
  bias_ln_kernel<<<BATCH * LKV, 256, 0, stream>>>(cat, bsr, gamma, beta);
  // kv = cat @ Wkv^T                   (5120 x 512, K=256)
  gemm_nt<<<dim3(8, 80), 256, 0, stream>>>(cat, Wkv, nullptr, kvb, BATCH * LKV, 512, 256);
  // attention (MFMA): z-part (1024 q vs 256 kv), x-part (4096 q vs 1280 kv)
  attn_mfma<<<32 * 16, 256, 0, stream>>>(q_buf, kvb, attn_out, 0, 256, 16);
  attn_mfma<<<32 * 64, 256, 0, stream>>>(q_buf, kvb, attn_out, NZ, LKV, 64);
  // out = attn_out @ Wproj^T + bproj   (20480 x 256, K=256)
  gemm_nt<<<dim3(4, 320), 256, 0, stream>>>(attn_out, Wproj, bproj, out, BATCH * NTOK, 256, 256);
}